// Round 1
// baseline (389.078 us; speedup 1.0000x reference)
//
#include <hip/hip_runtime.h>
#include <stdint.h>

typedef unsigned short u16;
typedef __attribute__((ext_vector_type(4))) unsigned short u16x4;
typedef __attribute__((ext_vector_type(8))) unsigned short u16x8;
typedef __attribute__((ext_vector_type(8))) __bf16 bf16x8;
typedef __attribute__((ext_vector_type(4))) float f32x4;

#define S_LEN 4096
#define D_DIM 1024
#define NH    16
#define HD    64

__device__ __forceinline__ u16 f2bf(float f) {
  uint32_t u = __builtin_bit_cast(uint32_t, f);
  return (u16)((u + 0x7FFFu + ((u >> 16) & 1u)) >> 16);
}

__device__ __forceinline__ bf16x8 bc(u16x8 v) { return __builtin_bit_cast(bf16x8, v); }

// ---------------- fp32 -> bf16 conversion ----------------
__global__ __launch_bounds__(256) void conv_kernel(const float* __restrict__ src,
                                                   u16* __restrict__ dst, int n4) {
  int i = blockIdx.x * 256 + threadIdx.x;
  if (i >= n4) return;
  f32x4 v = ((const f32x4*)src)[i];
  u16x4 o;
  o[0] = f2bf(v[0]); o[1] = f2bf(v[1]); o[2] = f2bf(v[2]); o[3] = f2bf(v[3]);
  ((u16x4*)dst)[i] = o;
}

// ---------------- GEMM core: C[128x128] = A[M,K] * W[N,K]^T (bf16, fp32 acc) ----
// Manual swizzled LDS staging (conflict-free-ish), 16x16x32 MFMA, 4 waves 2x2.
__device__ __forceinline__ void gemm_core(const u16* __restrict__ A,
                                          const u16* __restrict__ W,
                                          int m0, int n0, int Kd,
                                          u16* As, u16* Bs, f32x4 acc[4][4]) {
  const int tid  = threadIdx.x;
  const int lane = tid & 63;
  const int wv   = tid >> 6;
  const int wr   = wv >> 1, wc = wv & 1;
  const int b    = lane & 15, quad = lane >> 4;

  const int g0 = tid, g1 = tid + 256;
  const int row0 = g0 >> 2, k80 = g0 & 3;
  const int row1 = g1 >> 2, k81 = g1 & 3;
  const int sa0 = row0 * 32 + ((k80 ^ (row0 & 3)) * 8);
  const int sa1 = row1 * 32 + ((k81 ^ (row1 & 3)) * 8);

  for (int k0 = 0; k0 < Kd; k0 += 32) {
    u16x8 a0 = *(const u16x8*)(A + (size_t)(m0 + row0) * Kd + k0 + k80 * 8);
    u16x8 a1 = *(const u16x8*)(A + (size_t)(m0 + row1) * Kd + k0 + k81 * 8);
    u16x8 b0 = *(const u16x8*)(W + (size_t)(n0 + row0) * Kd + k0 + k80 * 8);
    u16x8 b1 = *(const u16x8*)(W + (size_t)(n0 + row1) * Kd + k0 + k81 * 8);
    *(u16x8*)(As + sa0) = a0;
    *(u16x8*)(As + sa1) = a1;
    *(u16x8*)(Bs + sa0) = b0;
    *(u16x8*)(Bs + sa1) = b1;
    __syncthreads();

    u16x8 af[4], bf[4];
#pragma unroll
    for (int i = 0; i < 4; ++i) {
      int r = wr * 64 + i * 16 + b;
      af[i] = *(const u16x8*)(As + r * 32 + ((quad ^ (b & 3)) * 8));
      int c = wc * 64 + i * 16 + b;
      bf[i] = *(const u16x8*)(Bs + c * 32 + ((quad ^ (b & 3)) * 8));
    }
#pragma unroll
    for (int i = 0; i < 4; ++i)
#pragma unroll
      for (int j = 0; j < 4; ++j)
        acc[i][j] = __builtin_amdgcn_mfma_f32_16x16x32_bf16(bc(af[i]), bc(bf[j]), acc[i][j], 0, 0, 0);
    __syncthreads();
  }
}

// ---------------- fused QKV projection ----------------
// z=0: Q = (x Wq^T) * 0.125, bf16 [S,D]
// z=1: K =  x Wk^T,          bf16 [S,D]
// z=2: Vt = (x Wv^T)^T,      bf16 [D,S]  (transposed store for attention PV frags)
__global__ __launch_bounds__(256) void gemm_qkv_kernel(const u16* __restrict__ X,
                                                       const u16* __restrict__ Wq,
                                                       const u16* __restrict__ Wk,
                                                       const u16* __restrict__ Wv,
                                                       u16* __restrict__ Q,
                                                       u16* __restrict__ K,
                                                       u16* __restrict__ Vt) {
  __shared__ __align__(16) u16 As[128 * 32];
  __shared__ __align__(16) u16 Bs[128 * 32];
  const int z = blockIdx.z;
  const u16* W = (z == 0) ? Wq : (z == 1) ? Wk : Wv;
  const int n0 = blockIdx.x * 128, m0 = blockIdx.y * 128;

  const f32x4 zero4 = {0.f, 0.f, 0.f, 0.f};
  f32x4 acc[4][4];
#pragma unroll
  for (int i = 0; i < 4; ++i)
#pragma unroll
    for (int j = 0; j < 4; ++j) acc[i][j] = zero4;

  gemm_core(X, W, m0, n0, D_DIM, As, Bs, acc);

  const int lane = threadIdx.x & 63;
  const int wv = threadIdx.x >> 6, wr = wv >> 1, wc = wv & 1;
  const int b = lane & 15, quad = lane >> 4;

  if (z < 2) {
    u16* out = (z == 0) ? Q : K;
    const float sc = (z == 0) ? 0.125f : 1.0f;
#pragma unroll
    for (int i = 0; i < 4; ++i)
#pragma unroll
      for (int j = 0; j < 4; ++j)
#pragma unroll
        for (int r = 0; r < 4; ++r) {
          int row = m0 + wr * 64 + i * 16 + quad * 4 + r;
          int col = n0 + wc * 64 + j * 16 + b;
          out[(size_t)row * D_DIM + col] = f2bf(acc[i][j][r] * sc);
        }
  } else {
#pragma unroll
    for (int i = 0; i < 4; ++i)
#pragma unroll
      for (int j = 0; j < 4; ++j) {
        int col = n0 + wc * 64 + j * 16 + b;           // d index
        int row = m0 + wr * 64 + i * 16 + quad * 4;    // s index (4 consecutive)
        u16x4 vv;
#pragma unroll
        for (int r = 0; r < 4; ++r) vv[r] = f2bf(acc[i][j][r]);
        *(u16x4*)(Vt + (size_t)col * S_LEN + row) = vv;
      }
  }
}

// ---------------- flash attention (causal) ----------------
// grid = (64 q-tiles, 16 heads), block = 256 (4 waves), q-tile = 64 rows.
__global__ __launch_bounds__(256) void attn_kernel(const u16* __restrict__ Q,
                                                   const u16* __restrict__ K,
                                                   const u16* __restrict__ Vt,
                                                   u16* __restrict__ Ctx) {
  const int qt = (int)gridDim.x - 1 - (int)blockIdx.x;  // big tiles first
  const int h  = blockIdx.y;
  const int tid = threadIdx.x, lane = tid & 63, w = tid >> 6;
  const int quad = lane >> 4, b = lane & 15;
  const int q0 = qt * 64;

  __shared__ __align__(16) u16 Ks[64 * 64];
  __shared__ __align__(16) u16 Vts[64 * 64];
  __shared__ __align__(16) u16 Ps[4][16 * 72];   // per-wave, stride 72 kills conflicts

  // Q fragments (A-operand): row = q0+16w+b, k = ks*32 + quad*8 + j
  u16x8 aq[2];
  {
    const size_t qbase = (size_t)(q0 + w * 16 + b) * D_DIM + h * HD + quad * 8;
    aq[0] = *(const u16x8*)(Q + qbase);
    aq[1] = *(const u16x8*)(Q + qbase + 32);
  }

  const f32x4 zero4 = {0.f, 0.f, 0.f, 0.f};
  f32x4 o[4];
#pragma unroll
  for (int jt = 0; jt < 4; ++jt) o[jt] = zero4;
  float m_run[4], l_run[4];
#pragma unroll
  for (int r = 0; r < 4; ++r) { m_run[r] = -3.0e38f; l_run[r] = 0.f; }

  const int srow = w * 16 + b;  // staging row this lane handles (0..63)
  u16* PsW = &Ps[w][0];
  const int nkv = qt + 1;

  for (int t = 0; t < nkv; ++t) {
    const int kv0 = t * 64;
    // ---- stage K tile [kv,d] and Vt tile [d,kv], XOR-swizzled ----
#pragma unroll
    for (int it = 0; it < 2; ++it) {
      int d8 = quad + it * 4;
      u16x8 kvv = *(const u16x8*)(K + (size_t)(kv0 + srow) * D_DIM + h * HD + d8 * 8);
      u16x8 vvv = *(const u16x8*)(Vt + (size_t)(h * HD + srow) * S_LEN + kv0 + d8 * 8);
      int sidx = srow * 64 + ((d8 ^ (srow & 7)) * 8);
      *(u16x8*)(Ks + sidx)  = kvv;
      *(u16x8*)(Vts + sidx) = vvv;
    }
    __syncthreads();

    // ---- S = Q K^T (rows: wave strip q0+16w..+15; cols: kv0..kv0+63) ----
    f32x4 s[4];
#pragma unroll
    for (int jt = 0; jt < 4; ++jt) {
      s[jt] = zero4;
      int n = jt * 16 + b;
#pragma unroll
      for (int ks = 0; ks < 2; ++ks) {
        u16x8 bk = *(const u16x8*)(Ks + n * 64 + (((ks * 4 + quad) ^ (b & 7)) * 8));
        s[jt] = __builtin_amdgcn_mfma_f32_16x16x32_bf16(bc(aq[ks]), bc(bk), s[jt], 0, 0, 0);
      }
    }

    // ---- causal mask (diagonal tile only) ----
    if (t == qt) {
      int rowb = q0 + w * 16 + quad * 4;
#pragma unroll
      for (int jt = 0; jt < 4; ++jt) {
        int col = kv0 + jt * 16 + b;
#pragma unroll
        for (int r = 0; r < 4; ++r)
          if (col > rowb + r) s[jt][r] = -1.0e30f;
      }
    }

    // ---- online softmax (rows quad*4+r; reduce over 16 lanes of quad group) ----
    float mx[4];
#pragma unroll
    for (int r = 0; r < 4; ++r)
      mx[r] = fmaxf(fmaxf(s[0][r], s[1][r]), fmaxf(s[2][r], s[3][r]));
#pragma unroll
    for (int off = 1; off < 16; off <<= 1)
#pragma unroll
      for (int r = 0; r < 4; ++r) mx[r] = fmaxf(mx[r], __shfl_xor(mx[r], off));

    float alpha[4], sum[4];
#pragma unroll
    for (int r = 0; r < 4; ++r) {
      float mn = fmaxf(m_run[r], mx[r]);
      alpha[r] = __expf(m_run[r] - mn);
      m_run[r] = mn;
      sum[r] = 0.f;
    }
#pragma unroll
    for (int jt = 0; jt < 4; ++jt)
#pragma unroll
      for (int r = 0; r < 4; ++r) {
        float p = __expf(s[jt][r] - m_run[r]);
        sum[r] += p;
        PsW[(quad * 4 + r) * 72 + jt * 16 + b] = f2bf(p);
      }
#pragma unroll
    for (int off = 1; off < 16; off <<= 1)
#pragma unroll
      for (int r = 0; r < 4; ++r) sum[r] += __shfl_xor(sum[r], off);
#pragma unroll
    for (int r = 0; r < 4; ++r) l_run[r] = l_run[r] * alpha[r] + sum[r];

    f32x4 al = {alpha[0], alpha[1], alpha[2], alpha[3]};
#pragma unroll
    for (int jt = 0; jt < 4; ++jt) o[jt] *= al;

    // ---- O += P V  (P via LDS round-trip: C-layout -> A-layout) ----
    u16x8 ap[2];
    ap[0] = *(const u16x8*)(PsW + b * 72 + quad * 8);
    ap[1] = *(const u16x8*)(PsW + b * 72 + 32 + quad * 8);
#pragma unroll
    for (int jt = 0; jt < 4; ++jt) {
      int dn = jt * 16 + b;
#pragma unroll
      for (int ks = 0; ks < 2; ++ks) {
        u16x8 bv = *(const u16x8*)(Vts + dn * 64 + (((ks * 4 + quad) ^ (b & 7)) * 8));
        o[jt] = __builtin_amdgcn_mfma_f32_16x16x32_bf16(bc(ap[ks]), bc(bv), o[jt], 0, 0, 0);
      }
    }
    __syncthreads();
  }

  // ---- epilogue: ctx[s, h*64+d] bf16 ----
#pragma unroll
  for (int jt = 0; jt < 4; ++jt)
#pragma unroll
    for (int r = 0; r < 4; ++r) {
      int row = q0 + w * 16 + quad * 4 + r;
      int col = h * HD + jt * 16 + b;
      Ctx[(size_t)row * D_DIM + col] = f2bf(o[jt][r] / l_run[r]);
    }
}

// ---------------- output projection: out = ctx Wo^T + bo (fp32 out) ----------
__global__ __launch_bounds__(256) void gemm_out_kernel(const u16* __restrict__ Ctx,
                                                       const u16* __restrict__ Wo,
                                                       const float* __restrict__ bo,
                                                       float* __restrict__ out) {
  __shared__ __align__(16) u16 As[128 * 32];
  __shared__ __align__(16) u16 Bs[128 * 32];
  const int n0 = blockIdx.x * 128, m0 = blockIdx.y * 128;

  const f32x4 zero4 = {0.f, 0.f, 0.f, 0.f};
  f32x4 acc[4][4];
#pragma unroll
  for (int i = 0; i < 4; ++i)
#pragma unroll
    for (int j = 0; j < 4; ++j) acc[i][j] = zero4;

  gemm_core(Ctx, Wo, m0, n0, D_DIM, As, Bs, acc);

  const int lane = threadIdx.x & 63;
  const int wv = threadIdx.x >> 6, wr = wv >> 1, wc = wv & 1;
  const int b = lane & 15, quad = lane >> 4;

#pragma unroll
  for (int j = 0; j < 4; ++j) {
    int col = n0 + wc * 64 + j * 16 + b;
    float bias = bo[col];
#pragma unroll
    for (int i = 0; i < 4; ++i)
#pragma unroll
      for (int r = 0; r < 4; ++r) {
        int row = m0 + wr * 64 + i * 16 + quad * 4 + r;
        out[(size_t)row * D_DIM + col] = acc[i][j][r] + bias;
      }
  }
}

// ---------------- launcher ----------------
extern "C" void kernel_launch(void* const* d_in, const int* in_sizes, int n_in,
                              void* d_out, int out_size, void* d_ws, size_t ws_size,
                              hipStream_t stream) {
  const float* x  = (const float*)d_in[0];
  const float* Wq = (const float*)d_in[1];
  const float* Wk = (const float*)d_in[2];
  const float* Wv = (const float*)d_in[3];
  const float* Wo = (const float*)d_in[4];
  const float* bo = (const float*)d_in[5];
  float* out = (float*)d_out;

  char* ws = (char*)d_ws;
  const size_t MB = 1u << 20;
  u16* Xb  = (u16*)(ws + 0 * MB);    // 8 MB  [S,D] bf16
  u16* Wqb = (u16*)(ws + 8 * MB);    // 2 MB
  u16* Wkb = (u16*)(ws + 10 * MB);   // 2 MB
  u16* Wvb = (u16*)(ws + 12 * MB);   // 2 MB
  u16* Wob = (u16*)(ws + 14 * MB);   // 2 MB
  u16* Qb  = (u16*)(ws + 16 * MB);   // 8 MB  [S,D] (scaled by 0.125)
  u16* Kb  = (u16*)(ws + 24 * MB);   // 8 MB  [S,D]
  u16* Vtb = (u16*)(ws + 32 * MB);   // 8 MB  [D,S] (transposed)
  u16* Cxb = (u16*)(ws + 40 * MB);   // 8 MB  [S,D]

  conv_kernel<<<4096, 256, 0, stream>>>(x,  Xb,  (S_LEN * D_DIM) / 4);
  conv_kernel<<<1024, 256, 0, stream>>>(Wq, Wqb, (D_DIM * D_DIM) / 4);
  conv_kernel<<<1024, 256, 0, stream>>>(Wk, Wkb, (D_DIM * D_DIM) / 4);
  conv_kernel<<<1024, 256, 0, stream>>>(Wv, Wvb, (D_DIM * D_DIM) / 4);
  conv_kernel<<<1024, 256, 0, stream>>>(Wo, Wob, (D_DIM * D_DIM) / 4);

  gemm_qkv_kernel<<<dim3(D_DIM / 128, S_LEN / 128, 3), 256, 0, stream>>>(
      Xb, Wqb, Wkb, Wvb, Qb, Kb, Vtb);

  attn_kernel<<<dim3(S_LEN / 64, NH), 256, 0, stream>>>(Qb, Kb, Vtb, Cxb);

  gemm_out_kernel<<<dim3(D_DIM / 128, S_LEN / 128), 256, 0, stream>>>(Cxb, Wob, bo, out);
}

// Round 2
// 302.684 us; speedup vs baseline: 1.2854x; 1.2854x over previous
//
#include <hip/hip_runtime.h>
#include <stdint.h>

typedef unsigned short u16;
typedef __attribute__((ext_vector_type(4))) unsigned short u16x4;
typedef __attribute__((ext_vector_type(8))) unsigned short u16x8;
typedef __attribute__((ext_vector_type(8))) __bf16 bf16x8;
typedef __attribute__((ext_vector_type(4))) float f32x4;

#define S_LEN 4096
#define D_DIM 1024
#define NH    16
#define HD    64

__device__ __forceinline__ u16 f2bf(float f) {
  uint32_t u = __builtin_bit_cast(uint32_t, f);
  return (u16)((u + 0x7FFFu + ((u >> 16) & 1u)) >> 16);
}
__device__ __forceinline__ float bf2f(u16 v) {
  return __builtin_bit_cast(float, (uint32_t)v << 16);
}
__device__ __forceinline__ bf16x8 bc(u16x8 v) { return __builtin_bit_cast(bf16x8, v); }
__device__ __forceinline__ float fexp2(float x) { return __builtin_amdgcn_exp2f(x); }

// ---------------- fp32 -> bf16 conversion ----------------
__global__ __launch_bounds__(256) void conv_kernel(const float* __restrict__ src,
                                                   u16* __restrict__ dst, int n4) {
  int i = blockIdx.x * 256 + threadIdx.x;
  if (i >= n4) return;
  f32x4 v = ((const f32x4*)src)[i];
  u16x4 o;
  o[0] = f2bf(v[0]); o[1] = f2bf(v[1]); o[2] = f2bf(v[2]); o[3] = f2bf(v[3]);
  ((u16x4*)dst)[i] = o;
}

// ---------------- GEMM core: C[128x128] = A[M,K] * W[N,K]^T (bf16, fp32 acc) ----
__device__ __forceinline__ void gemm_core(const u16* __restrict__ A,
                                          const u16* __restrict__ W,
                                          int m0, int n0, int Kd,
                                          u16* As, u16* Bs, f32x4 acc[4][4]) {
  const int tid  = threadIdx.x;
  const int lane = tid & 63;
  const int wv   = tid >> 6;
  const int wr   = wv >> 1, wc = wv & 1;
  const int b    = lane & 15, quad = lane >> 4;

  const int g0 = tid, g1 = tid + 256;
  const int row0 = g0 >> 2, k80 = g0 & 3;
  const int row1 = g1 >> 2, k81 = g1 & 3;
  const int sa0 = row0 * 32 + ((k80 ^ (row0 & 3)) * 8);
  const int sa1 = row1 * 32 + ((k81 ^ (row1 & 3)) * 8);

  for (int k0 = 0; k0 < Kd; k0 += 32) {
    u16x8 a0 = *(const u16x8*)(A + (size_t)(m0 + row0) * Kd + k0 + k80 * 8);
    u16x8 a1 = *(const u16x8*)(A + (size_t)(m0 + row1) * Kd + k0 + k81 * 8);
    u16x8 b0 = *(const u16x8*)(W + (size_t)(n0 + row0) * Kd + k0 + k80 * 8);
    u16x8 b1 = *(const u16x8*)(W + (size_t)(n0 + row1) * Kd + k0 + k81 * 8);
    *(u16x8*)(As + sa0) = a0;
    *(u16x8*)(As + sa1) = a1;
    *(u16x8*)(Bs + sa0) = b0;
    *(u16x8*)(Bs + sa1) = b1;
    __syncthreads();

    u16x8 af[4], bf[4];
#pragma unroll
    for (int i = 0; i < 4; ++i) {
      int r = wr * 64 + i * 16 + b;
      af[i] = *(const u16x8*)(As + r * 32 + ((quad ^ (b & 3)) * 8));
      int c = wc * 64 + i * 16 + b;
      bf[i] = *(const u16x8*)(Bs + c * 32 + ((quad ^ (b & 3)) * 8));
    }
#pragma unroll
    for (int i = 0; i < 4; ++i)
#pragma unroll
      for (int j = 0; j < 4; ++j)
        acc[i][j] = __builtin_amdgcn_mfma_f32_16x16x32_bf16(bc(af[i]), bc(bf[j]), acc[i][j], 0, 0, 0);
    __syncthreads();
  }
}

// ---------------- fused QKV projection ----------------
// z=0: Q = (x Wq^T) * (log2(e)/8)  -> scores come out in exp2 domain
// z=1: K =  x Wk^T,          bf16 [S,D]
// z=2: Vt = (x Wv^T)^T,      bf16 [D,S]
__global__ __launch_bounds__(256) void gemm_qkv_kernel(const u16* __restrict__ X,
                                                       const u16* __restrict__ Wq,
                                                       const u16* __restrict__ Wk,
                                                       const u16* __restrict__ Wv,
                                                       u16* __restrict__ Q,
                                                       u16* __restrict__ K,
                                                       u16* __restrict__ Vt) {
  __shared__ __align__(16) u16 As[128 * 32];
  __shared__ __align__(16) u16 Bs[128 * 32];
  const int z = blockIdx.z;
  const u16* W = (z == 0) ? Wq : (z == 1) ? Wk : Wv;
  const int n0 = blockIdx.x * 128, m0 = blockIdx.y * 128;

  const f32x4 zero4 = {0.f, 0.f, 0.f, 0.f};
  f32x4 acc[4][4];
#pragma unroll
  for (int i = 0; i < 4; ++i)
#pragma unroll
    for (int j = 0; j < 4; ++j) acc[i][j] = zero4;

  gemm_core(X, W, m0, n0, D_DIM, As, Bs, acc);

  const int lane = threadIdx.x & 63;
  const int wv = threadIdx.x >> 6, wr = wv >> 1, wc = wv & 1;
  const int b = lane & 15, quad = lane >> 4;

  if (z < 2) {
    u16* out = (z == 0) ? Q : K;
    // 0.125 * log2(e): fold softmax scale AND exp->exp2 conversion into Q
    const float sc = (z == 0) ? 0.18033688011112042f : 1.0f;
#pragma unroll
    for (int i = 0; i < 4; ++i)
#pragma unroll
      for (int j = 0; j < 4; ++j)
#pragma unroll
        for (int r = 0; r < 4; ++r) {
          int row = m0 + wr * 64 + i * 16 + quad * 4 + r;
          int col = n0 + wc * 64 + j * 16 + b;
          out[(size_t)row * D_DIM + col] = f2bf(acc[i][j][r] * sc);
        }
  } else {
#pragma unroll
    for (int i = 0; i < 4; ++i)
#pragma unroll
      for (int j = 0; j < 4; ++j) {
        int col = n0 + wc * 64 + j * 16 + b;           // d index
        int row = m0 + wr * 64 + i * 16 + quad * 4;    // s index (4 consecutive)
        u16x4 vv;
#pragma unroll
        for (int r = 0; r < 4; ++r) vv[r] = f2bf(acc[i][j][r]);
        *(u16x4*)(Vt + (size_t)col * S_LEN + row) = vv;
      }
  }
}

// ---------------- flash attention, kv-split (causal) ----------------
// Work unit = (head, 64-row q-tile, chunk of <=16 kv-tiles). 160 units/head,
// 2560 blocks total, max 16 iters each (balanced). Partials: unnormalized
// O (bf16 [64][64]) + m,l (f32[64] each) per unit; combined by attn_combine.
// Double-buffered K/V LDS + register prefetch -> 1 barrier per kv-tile.
__global__ __launch_bounds__(256) void attn_kernel(const u16* __restrict__ Q,
                                                   const u16* __restrict__ K,
                                                   const u16* __restrict__ Vt,
                                                   u16* __restrict__ Opart,
                                                   float* __restrict__ ml) {
  const int u = (int)gridDim.x - 1 - (int)blockIdx.x;  // 16-tile chunks first
  const int h = u / 160;
  const int uu = u - h * 160;
  int qt, c;
  if (uu < 16)      { qt = uu;                c = 0; }
  else if (uu < 48) { qt = 16 + ((uu - 16) >> 1); c = (uu - 16) & 1; }
  else if (uu < 96) { qt = 32 + (uu - 48) / 3;    c = (uu - 48) % 3; }
  else              { qt = 48 + ((uu - 96) >> 2); c = (uu - 96) & 3; }
  const int t0 = c * 16;
  const int t_end = min(t0 + 16, qt + 1);
  const int q0 = qt * 64;

  const int tid = threadIdx.x, lane = tid & 63, w = tid >> 6;
  const int quad = lane >> 4, b = lane & 15;

  __shared__ __align__(16) u16 Ks[2][64 * 64];
  __shared__ __align__(16) u16 Vts[2][64 * 64];
  __shared__ __align__(16) u16 Ps[4][16 * 72];

  // Q fragments (A-operand): row = q0+16w+b, k = ks*32 + quad*8 + j
  u16x8 aq[2];
  {
    const size_t qbase = (size_t)(q0 + w * 16 + b) * D_DIM + h * HD + quad * 8;
    aq[0] = *(const u16x8*)(Q + qbase);
    aq[1] = *(const u16x8*)(Q + qbase + 32);
  }

  const f32x4 zero4 = {0.f, 0.f, 0.f, 0.f};
  f32x4 o[4];
#pragma unroll
  for (int jt = 0; jt < 4; ++jt) o[jt] = zero4;
  float m_run[4], l_run[4];
#pragma unroll
  for (int r = 0; r < 4; ++r) { m_run[r] = -3.0e38f; l_run[r] = 0.f; }

  const int srow = w * 16 + b;  // staging row (0..63)
  const int sidx0 = srow * 64 + ((quad ^ (srow & 7)) * 8);
  const int sidx1 = srow * 64 + (((quad + 4) ^ (srow & 7)) * 8);
  u16* PsW = &Ps[w][0];

  // prefetch first tile into registers
  u16x8 kr0, kr1, vr0, vr1;
  {
    const size_t kb = (size_t)(t0 * 64 + srow) * D_DIM + h * HD;
    kr0 = *(const u16x8*)(K + kb + quad * 8);
    kr1 = *(const u16x8*)(K + kb + (quad + 4) * 8);
    const size_t vb = (size_t)(h * HD + srow) * S_LEN + t0 * 64;
    vr0 = *(const u16x8*)(Vt + vb + quad * 8);
    vr1 = *(const u16x8*)(Vt + vb + (quad + 4) * 8);
  }

  int buf = 0;
  for (int t = t0; t < t_end; ++t) {
    // ---- commit prefetched tile to LDS buf ----
    *(u16x8*)(&Ks[buf][sidx0])  = kr0;
    *(u16x8*)(&Ks[buf][sidx1])  = kr1;
    *(u16x8*)(&Vts[buf][sidx0]) = vr0;
    *(u16x8*)(&Vts[buf][sidx1]) = vr1;
    __syncthreads();

    // ---- prefetch next tile (overlaps with compute below) ----
    if (t + 1 < t_end) {
      const size_t kb = (size_t)((t + 1) * 64 + srow) * D_DIM + h * HD;
      kr0 = *(const u16x8*)(K + kb + quad * 8);
      kr1 = *(const u16x8*)(K + kb + (quad + 4) * 8);
      const size_t vb = (size_t)(h * HD + srow) * S_LEN + (t + 1) * 64;
      vr0 = *(const u16x8*)(Vt + vb + quad * 8);
      vr1 = *(const u16x8*)(Vt + vb + (quad + 4) * 8);
    }

    // ---- S = Q K^T (exp2 domain; scale folded into Q) ----
    f32x4 s[4];
#pragma unroll
    for (int jt = 0; jt < 4; ++jt) {
      s[jt] = zero4;
      int n = jt * 16 + b;
#pragma unroll
      for (int ks = 0; ks < 2; ++ks) {
        u16x8 bk = *(const u16x8*)(&Ks[buf][n * 64 + (((ks * 4 + quad) ^ (b & 7)) * 8)]);
        s[jt] = __builtin_amdgcn_mfma_f32_16x16x32_bf16(bc(aq[ks]), bc(bk), s[jt], 0, 0, 0);
      }
    }

    // ---- causal mask (diagonal tile only) ----
    if (t == qt) {
      int rowb = q0 + w * 16 + quad * 4;
      int kv0 = t * 64;
#pragma unroll
      for (int jt = 0; jt < 4; ++jt) {
        int col = kv0 + jt * 16 + b;
#pragma unroll
        for (int r = 0; r < 4; ++r)
          if (col > rowb + r) s[jt][r] = -1.0e30f;
      }
    }

    // ---- online softmax (exp2 domain) ----
    float mx[4];
#pragma unroll
    for (int r = 0; r < 4; ++r)
      mx[r] = fmaxf(fmaxf(s[0][r], s[1][r]), fmaxf(s[2][r], s[3][r]));
#pragma unroll
    for (int off = 1; off < 16; off <<= 1)
#pragma unroll
      for (int r = 0; r < 4; ++r) mx[r] = fmaxf(mx[r], __shfl_xor(mx[r], off));

    float alpha[4], sum[4];
#pragma unroll
    for (int r = 0; r < 4; ++r) {
      float mn = fmaxf(m_run[r], mx[r]);
      alpha[r] = fexp2(m_run[r] - mn);
      m_run[r] = mn;
      sum[r] = 0.f;
    }
#pragma unroll
    for (int jt = 0; jt < 4; ++jt)
#pragma unroll
      for (int r = 0; r < 4; ++r) {
        float p = fexp2(s[jt][r] - m_run[r]);
        sum[r] += p;
        PsW[(quad * 4 + r) * 72 + jt * 16 + b] = f2bf(p);
      }
#pragma unroll
    for (int off = 1; off < 16; off <<= 1)
#pragma unroll
      for (int r = 0; r < 4; ++r) sum[r] += __shfl_xor(sum[r], off);
#pragma unroll
    for (int r = 0; r < 4; ++r) l_run[r] = l_run[r] * alpha[r] + sum[r];

    f32x4 al = {alpha[0], alpha[1], alpha[2], alpha[3]};
#pragma unroll
    for (int jt = 0; jt < 4; ++jt) o[jt] *= al;

    // ---- O += P V (P via per-wave LDS round-trip: C-layout -> A-layout) ----
    u16x8 ap[2];
    ap[0] = *(const u16x8*)(PsW + b * 72 + quad * 8);
    ap[1] = *(const u16x8*)(PsW + b * 72 + 32 + quad * 8);
#pragma unroll
    for (int jt = 0; jt < 4; ++jt) {
      int dn = jt * 16 + b;
#pragma unroll
      for (int ks = 0; ks < 2; ++ks) {
        u16x8 bv = *(const u16x8*)(&Vts[buf][dn * 64 + (((ks * 4 + quad) ^ (b & 7)) * 8)]);
        o[jt] = __builtin_amdgcn_mfma_f32_16x16x32_bf16(bc(ap[ks]), bc(bv), o[jt], 0, 0, 0);
      }
    }
    buf ^= 1;
  }

  // ---- write partials: unnormalized O (bf16), m/l (f32) ----
  const size_t ob = (size_t)u * 4096;
#pragma unroll
  for (int jt = 0; jt < 4; ++jt)
#pragma unroll
    for (int r = 0; r < 4; ++r)
      Opart[ob + (size_t)(w * 16 + quad * 4 + r) * 64 + jt * 16 + b] = f2bf(o[jt][r]);
  if (b == 0) {
    const size_t mb = (size_t)u * 128 + w * 16 + quad * 4;
#pragma unroll
    for (int r = 0; r < 4; ++r) {
      ml[mb + r]      = m_run[r];
      ml[mb + 64 + r] = l_run[r];
    }
  }
}

// ---------------- combine kv-split partials -> Ctx (bf16 [S,D]) ----------------
__global__ __launch_bounds__(256) void attn_combine_kernel(const u16* __restrict__ Opart,
                                                           const float* __restrict__ ml,
                                                           u16* __restrict__ Ctx) {
  const int hq = blockIdx.x;          // 0..1023
  const int h = hq >> 6, qt = hq & 63;
  int base;
  if (qt < 16)      base = qt;
  else if (qt < 32) base = 2 * qt - 16;
  else if (qt < 48) base = 3 * qt - 48;
  else              base = 4 * qt - 96;
  base += h * 160;
  const int nc = 1 + (qt >> 4);

  const int tid = threadIdx.x;
  const int row = tid >> 2;           // 0..63
  const int dg  = (tid & 3) * 16;     // d-group base

  float M = -3.0e38f;
  for (int ci = 0; ci < nc; ++ci)
    M = fmaxf(M, ml[(size_t)(base + ci) * 128 + row]);

  float L = 0.f;
  float acc[16];
#pragma unroll
  for (int i = 0; i < 16; ++i) acc[i] = 0.f;

  for (int ci = 0; ci < nc; ++ci) {
    float mp = ml[(size_t)(base + ci) * 128 + row];
    float lp = ml[(size_t)(base + ci) * 128 + 64 + row];
    float wgt = fexp2(mp - M);
    L += lp * wgt;
    const u16* op = Opart + (size_t)(base + ci) * 4096 + row * 64 + dg;
    u16x8 v0 = *(const u16x8*)op;
    u16x8 v1 = *(const u16x8*)(op + 8);
#pragma unroll
    for (int i = 0; i < 8; ++i) acc[i] += bf2f(v0[i]) * wgt;
#pragma unroll
    for (int i = 0; i < 8; ++i) acc[i + 8] += bf2f(v1[i]) * wgt;
  }
  const float inv = 1.f / L;  // every row has >=1 unmasked col
  u16x8 o0, o1;
#pragma unroll
  for (int i = 0; i < 8; ++i) { o0[i] = f2bf(acc[i] * inv); o1[i] = f2bf(acc[i + 8] * inv); }
  u16* dst = Ctx + (size_t)(qt * 64 + row) * D_DIM + h * HD + dg;
  *(u16x8*)dst = o0;
  *(u16x8*)(dst + 8) = o1;
}

// ---------------- output projection: out = ctx Wo^T + bo (fp32 out) ----------
__global__ __launch_bounds__(256) void gemm_out_kernel(const u16* __restrict__ Ctx,
                                                       const u16* __restrict__ Wo,
                                                       const float* __restrict__ bo,
                                                       float* __restrict__ out) {
  __shared__ __align__(16) u16 As[128 * 32];
  __shared__ __align__(16) u16 Bs[128 * 32];
  const int n0 = blockIdx.x * 128, m0 = blockIdx.y * 128;

  const f32x4 zero4 = {0.f, 0.f, 0.f, 0.f};
  f32x4 acc[4][4];
#pragma unroll
  for (int i = 0; i < 4; ++i)
#pragma unroll
    for (int j = 0; j < 4; ++j) acc[i][j] = zero4;

  gemm_core(Ctx, Wo, m0, n0, D_DIM, As, Bs, acc);

  const int lane = threadIdx.x & 63;
  const int wv = threadIdx.x >> 6, wr = wv >> 1, wc = wv & 1;
  const int b = lane & 15, quad = lane >> 4;

#pragma unroll
  for (int j = 0; j < 4; ++j) {
    int col = n0 + wc * 64 + j * 16 + b;
    float bias = bo[col];
#pragma unroll
    for (int i = 0; i < 4; ++i)
#pragma unroll
      for (int r = 0; r < 4; ++r) {
        int row = m0 + wr * 64 + i * 16 + quad * 4 + r;
        out[(size_t)row * D_DIM + col] = acc[i][j][r] + bias;
      }
  }
}

// ---------------- launcher ----------------
extern "C" void kernel_launch(void* const* d_in, const int* in_sizes, int n_in,
                              void* d_out, int out_size, void* d_ws, size_t ws_size,
                              hipStream_t stream) {
  const float* x  = (const float*)d_in[0];
  const float* Wq = (const float*)d_in[1];
  const float* Wk = (const float*)d_in[2];
  const float* Wv = (const float*)d_in[3];
  const float* Wo = (const float*)d_in[4];
  const float* bo = (const float*)d_in[5];
  float* out = (float*)d_out;

  char* ws = (char*)d_ws;
  const size_t MB = 1u << 20;
  u16*   Xb    = (u16*)(ws + 0 * MB);    // 8 MB  [S,D] bf16
  u16*   Wqb   = (u16*)(ws + 8 * MB);    // 2 MB
  u16*   Wkb   = (u16*)(ws + 10 * MB);   // 2 MB
  u16*   Wvb   = (u16*)(ws + 12 * MB);   // 2 MB
  u16*   Wob   = (u16*)(ws + 14 * MB);   // 2 MB
  u16*   Qb    = (u16*)(ws + 16 * MB);   // 8 MB  [S,D] (scaled by log2e/8)
  u16*   Kb    = (u16*)(ws + 24 * MB);   // 8 MB  [S,D]
  u16*   Vtb   = (u16*)(ws + 32 * MB);   // 8 MB  [D,S] (transposed)
  u16*   Cxb   = (u16*)(ws + 40 * MB);   // 8 MB  [S,D]
  u16*   Opart = (u16*)(ws + 48 * MB);   // 20 MB: 2560 units x 64x64 bf16
  float* mlbuf = (float*)(ws + 68 * MB); // 1.25 MB: 2560 x (m[64], l[64])

  conv_kernel<<<4096, 256, 0, stream>>>(x,  Xb,  (S_LEN * D_DIM) / 4);
  conv_kernel<<<1024, 256, 0, stream>>>(Wq, Wqb, (D_DIM * D_DIM) / 4);
  conv_kernel<<<1024, 256, 0, stream>>>(Wk, Wkb, (D_DIM * D_DIM) / 4);
  conv_kernel<<<1024, 256, 0, stream>>>(Wv, Wvb, (D_DIM * D_DIM) / 4);
  conv_kernel<<<1024, 256, 0, stream>>>(Wo, Wob, (D_DIM * D_DIM) / 4);

  gemm_qkv_kernel<<<dim3(D_DIM / 128, S_LEN / 128, 3), 256, 0, stream>>>(
      Xb, Wqb, Wkb, Wvb, Qb, Kb, Vtb);

  attn_kernel<<<dim3(2560), 256, 0, stream>>>(Qb, Kb, Vtb, Opart, mlbuf);

  attn_combine_kernel<<<dim3(1024), 256, 0, stream>>>(Opart, mlbuf, Cxb);

  gemm_out_kernel<<<dim3(D_DIM / 128, S_LEN / 128), 256, 0, stream>>>(Cxb, Wob, bo, out);
}

// Round 3
// 248.767 us; speedup vs baseline: 1.5640x; 1.2167x over previous
//
#include <hip/hip_runtime.h>
#include <stdint.h>

typedef unsigned short u16;
typedef __attribute__((ext_vector_type(4))) unsigned short u16x4;
typedef __attribute__((ext_vector_type(8))) unsigned short u16x8;
typedef __attribute__((ext_vector_type(8))) __bf16 bf16x8;
typedef __attribute__((ext_vector_type(4))) float f32x4;

#define S_LEN 4096
#define D_DIM 1024
#define NH    16
#define HD    64

__device__ __forceinline__ u16 f2bf(float f) {
  return __builtin_bit_cast(u16, (__bf16)f);   // hw RNE cvt on gfx950
}
__device__ __forceinline__ float bf2f(u16 v) {
  return __builtin_bit_cast(float, (uint32_t)v << 16);
}
__device__ __forceinline__ bf16x8 bc(u16x8 v) { return __builtin_bit_cast(bf16x8, v); }
__device__ __forceinline__ float fexp2(float x) { return __builtin_amdgcn_exp2f(x); }

// async global->LDS, 16B per lane; lds dest = wave-uniform base + lane*16B
__device__ __forceinline__ void gload16(const u16* g, u16* l) {
  __builtin_amdgcn_global_load_lds((__attribute__((address_space(1))) void*)g,
                                   (__attribute__((address_space(3))) void*)l, 16, 0, 0);
}

// ---------------- fp32 -> bf16 conversion ----------------
__global__ __launch_bounds__(256) void conv_kernel(const float* __restrict__ src,
                                                   u16* __restrict__ dst, int n4) {
  int i = blockIdx.x * 256 + threadIdx.x;
  if (i >= n4) return;
  f32x4 v = ((const f32x4*)src)[i];
  u16x4 o;
  o[0] = f2bf(v[0]); o[1] = f2bf(v[1]); o[2] = f2bf(v[2]); o[3] = f2bf(v[3]);
  ((u16x4*)dst)[i] = o;
}

// ---------------- GEMM core: C[128x128] = A[M,K] * W[N,K]^T (bf16, fp32 acc) ----
// m97 pattern: global_load_lds width-16 staging, unswizzled [row][32] LDS,
// 2-barrier K-loop, 16x16x32 MFMA, 4 waves 2x2.
__device__ __forceinline__ void gemm_core(const u16* __restrict__ A,
                                          const u16* __restrict__ W,
                                          int m0, int n0, int Kd,
                                          u16* As, u16* Bs, f32x4 acc[4][4]) {
  const int tid  = threadIdx.x;
  const int lane = tid & 63;
  const int wv   = tid >> 6;
  const int wr   = wv >> 1, wc = wv & 1;
  const int b    = lane & 15, quad = lane >> 4;
  const int lrow = lane >> 2, lkc = (lane & 3) * 8;

  const u16* ga0 = A + (size_t)(m0 + wv * 16 + lrow) * Kd + lkc;
  const u16* ga1 = A + (size_t)(m0 + 64 + wv * 16 + lrow) * Kd + lkc;
  const u16* gb0 = W + (size_t)(n0 + wv * 16 + lrow) * Kd + lkc;
  const u16* gb1 = W + (size_t)(n0 + 64 + wv * 16 + lrow) * Kd + lkc;
  u16* la0 = As + wv * 512;
  u16* la1 = As + 2048 + wv * 512;
  u16* lb0 = Bs + wv * 512;
  u16* lb1 = Bs + 2048 + wv * 512;

  for (int k0 = 0; k0 < Kd; k0 += 32) {
    gload16(ga0 + k0, la0);
    gload16(ga1 + k0, la1);
    gload16(gb0 + k0, lb0);
    gload16(gb1 + k0, lb1);
    __syncthreads();   // drains vmcnt (DMA) for own wave + block barrier

    u16x8 af[4], bw[4];
#pragma unroll
    for (int i = 0; i < 4; ++i) {
      af[i] = *(const u16x8*)(As + (wr * 64 + i * 16 + b) * 32 + quad * 8);
      bw[i] = *(const u16x8*)(Bs + (wc * 64 + i * 16 + b) * 32 + quad * 8);
    }
#pragma unroll
    for (int i = 0; i < 4; ++i)
#pragma unroll
      for (int j = 0; j < 4; ++j)
        acc[i][j] = __builtin_amdgcn_mfma_f32_16x16x32_bf16(bc(af[i]), bc(bw[j]), acc[i][j], 0, 0, 0);
    __syncthreads();
  }
}

// ---------------- fused QKV projection ----------------
// z=0: Q = (x Wq^T) * (log2(e)/8)  -> scores come out in exp2 domain
// z=1: K =  x Wk^T,          bf16 [S,D]
// z=2: Vt = (x Wv^T)^T,      bf16 [D,S]
__global__ __launch_bounds__(256) void gemm_qkv_kernel(const u16* __restrict__ X,
                                                       const u16* __restrict__ Wq,
                                                       const u16* __restrict__ Wk,
                                                       const u16* __restrict__ Wv,
                                                       u16* __restrict__ Q,
                                                       u16* __restrict__ K,
                                                       u16* __restrict__ Vt) {
  __shared__ __align__(16) u16 As[128 * 32];
  __shared__ __align__(16) u16 Bs[128 * 32];
  const int z = blockIdx.z;
  const u16* W = (z == 0) ? Wq : (z == 1) ? Wk : Wv;
  const int n0 = blockIdx.x * 128, m0 = blockIdx.y * 128;

  const f32x4 zero4 = {0.f, 0.f, 0.f, 0.f};
  f32x4 acc[4][4];
#pragma unroll
  for (int i = 0; i < 4; ++i)
#pragma unroll
    for (int j = 0; j < 4; ++j) acc[i][j] = zero4;

  gemm_core(X, W, m0, n0, D_DIM, As, Bs, acc);

  const int lane = threadIdx.x & 63;
  const int wv = threadIdx.x >> 6, wr = wv >> 1, wc = wv & 1;
  const int b = lane & 15, quad = lane >> 4;

  if (z < 2) {
    u16* out = (z == 0) ? Q : K;
    const float sc = (z == 0) ? 0.18033688011112042f : 1.0f;
#pragma unroll
    for (int i = 0; i < 4; ++i)
#pragma unroll
      for (int j = 0; j < 4; ++j)
#pragma unroll
        for (int r = 0; r < 4; ++r) {
          int row = m0 + wr * 64 + i * 16 + quad * 4 + r;
          int col = n0 + wc * 64 + j * 16 + b;
          out[(size_t)row * D_DIM + col] = f2bf(acc[i][j][r] * sc);
        }
  } else {
#pragma unroll
    for (int i = 0; i < 4; ++i)
#pragma unroll
      for (int j = 0; j < 4; ++j) {
        int col = n0 + wc * 64 + j * 16 + b;           // d index
        int row = m0 + wr * 64 + i * 16 + quad * 4;    // s index (4 consecutive)
        u16x4 vv;
#pragma unroll
        for (int r = 0; r < 4; ++r) vv[r] = f2bf(acc[i][j][r]);
        *(u16x4*)(Vt + (size_t)col * S_LEN + row) = vv;
      }
  }
}

// ---------------- flash attention, kv-split, transposed algebra (causal) -------
// S^T = K Q^T  and  O^T = V^T P^T: each lane's C-elements belong to ONE q-row
// (col=lane&15) -> scalar m/l/alpha, 2-shuffle reductions, vectorized P store.
// K/V staged via global_load_lds into [ks][64][32] halves, double-buffered.
__global__ __launch_bounds__(256) void attn_kernel(const u16* __restrict__ Q,
                                                   const u16* __restrict__ K,
                                                   const u16* __restrict__ Vt,
                                                   u16* __restrict__ Opart,
                                                   float* __restrict__ ml) {
  const int u = (int)gridDim.x - 1 - (int)blockIdx.x;  // 16-tile chunks first
  const int h = u / 160;
  const int uu = u - h * 160;
  int qt, c;
  if (uu < 16)      { qt = uu;                c = 0; }
  else if (uu < 48) { qt = 16 + ((uu - 16) >> 1); c = (uu - 16) & 1; }
  else if (uu < 96) { qt = 32 + (uu - 48) / 3;    c = (uu - 48) % 3; }
  else              { qt = 48 + ((uu - 96) >> 2); c = (uu - 96) & 3; }
  const int t0 = c * 16;
  const int t_end = min(t0 + 16, qt + 1);
  const int q0 = qt * 64;

  const int tid = threadIdx.x, lane = tid & 63, w = tid >> 6;
  const int quad = lane >> 4, b = lane & 15;
  const int lrow = lane >> 2, lkc = (lane & 3) * 8;

  __shared__ __align__(16) u16 Ks[2 * 4096];   // [buf][ks_d][kv 64][32]
  __shared__ __align__(16) u16 Vts[2 * 4096];  // [buf][ks_kv][d 64][32]
  __shared__ __align__(16) u16 Ps[4][16 * 72]; // per-wave [q 16][kv 64+pad]

  // Q fragments (B-operand): n = q row = b, k = d = ks*32 + quad*8 + j
  u16x8 bq[2];
  {
    const size_t qbase = (size_t)(q0 + w * 16 + b) * D_DIM + h * HD + quad * 8;
    bq[0] = *(const u16x8*)(Q + qbase);
    bq[1] = *(const u16x8*)(Q + qbase + 32);
  }

  const f32x4 zero4 = {0.f, 0.f, 0.f, 0.f};
  f32x4 o[4];   // O^T tiles: row = d = jt*16+quad*4+r, col = q = b
#pragma unroll
  for (int jt = 0; jt < 4; ++jt) o[jt] = zero4;
  float m_run = -3.0e38f, l_run = 0.f;

  auto stage = [&](int t, int bsel) {
    const int kv0s = t * 64;
    const u16* kg = K + (size_t)(kv0s + w * 16 + lrow) * D_DIM + h * HD + lkc;
    const u16* vg = Vt + (size_t)(h * HD + w * 16 + lrow) * S_LEN + kv0s + lkc;
    u16* kbase = Ks + bsel * 4096 + w * 512;
    u16* vbase = Vts + bsel * 4096 + w * 512;
    gload16(kg, kbase);                 // d 0..31 half
    gload16(kg + 32, kbase + 2048);     // d 32..63 half
    gload16(vg, vbase);                 // kv 0..31 half
    gload16(vg + 32, vbase + 2048);     // kv 32..63 half
  };

  u16* PsW = &Ps[w][0];
  stage(t0, 0);
  int buf = 0;

  for (int t = t0; t < t_end; ++t) {
    __syncthreads();   // drain DMA into buf; all waves done with buf^1 compute
    if (t + 1 < t_end) stage(t + 1, buf ^ 1);
    const u16* KB = Ks + buf * 4096;
    const u16* VB = Vts + buf * 4096;

    // ---- S^T = K Q^T : s[jt] rows = kv jt*16..+15, cols = 16 q rows ----
    f32x4 s[4];
#pragma unroll
    for (int jt = 0; jt < 4; ++jt) {
      s[jt] = zero4;
#pragma unroll
      for (int ks = 0; ks < 2; ++ks) {
        u16x8 ak = *(const u16x8*)(KB + ks * 2048 + (jt * 16 + b) * 32 + quad * 8);
        s[jt] = __builtin_amdgcn_mfma_f32_16x16x32_bf16(bc(ak), bc(bq[ks]), s[jt], 0, 0, 0);
      }
    }

    // ---- causal mask (diagonal tile only): kv > q -> -inf ----
    if (t == qt) {
      const int qg = q0 + w * 16 + b;
      const int kvb = t * 64 + quad * 4;
#pragma unroll
      for (int jt = 0; jt < 4; ++jt)
#pragma unroll
        for (int r = 0; r < 4; ++r)
          if (kvb + jt * 16 + r > qg) s[jt][r] = -1.0e30f;
    }

    // ---- online softmax (exp2 domain), per-lane scalar stats ----
    float mx = s[0][0];
#pragma unroll
    for (int jt = 0; jt < 4; ++jt)
#pragma unroll
      for (int r = 0; r < 4; ++r) mx = fmaxf(mx, s[jt][r]);
    mx = fmaxf(mx, __shfl_xor(mx, 16));
    mx = fmaxf(mx, __shfl_xor(mx, 32));

    const float mn = fmaxf(m_run, mx);
    const float alpha = fexp2(m_run - mn);
    m_run = mn;

    float sum = 0.f;
#pragma unroll
    for (int jt = 0; jt < 4; ++jt) {
      u16x4 pk;
#pragma unroll
      for (int r = 0; r < 4; ++r) {
        float p = fexp2(s[jt][r] - mn);
        sum += p;
        pk[r] = f2bf(p);
      }
      *(u16x4*)(PsW + b * 72 + jt * 16 + quad * 4) = pk;   // Ps[q=b][kv]
    }
    sum += __shfl_xor(sum, 16);
    sum += __shfl_xor(sum, 32);
    l_run = l_run * alpha + sum;

#pragma unroll
    for (int jt = 0; jt < 4; ++jt) o[jt] *= alpha;

    // ---- O^T += V^T P^T ----
    u16x8 bp[2];
    bp[0] = *(const u16x8*)(PsW + b * 72 + quad * 8);        // B: k=kv, n=q=b
    bp[1] = *(const u16x8*)(PsW + b * 72 + 32 + quad * 8);
#pragma unroll
    for (int jt = 0; jt < 4; ++jt)
#pragma unroll
      for (int ks = 0; ks < 2; ++ks) {
        u16x8 av = *(const u16x8*)(VB + ks * 2048 + (jt * 16 + b) * 32 + quad * 8);
        o[jt] = __builtin_amdgcn_mfma_f32_16x16x32_bf16(bc(av), bc(bp[ks]), o[jt], 0, 0, 0);
      }
    buf ^= 1;
  }

  // ---- write partials: Opart unit layout [q 64][d 64], vectorized over d ----
  const size_t ob = (size_t)u * 4096 + (size_t)(w * 16 + b) * 64 + quad * 4;
#pragma unroll
  for (int jt = 0; jt < 4; ++jt) {
    u16x4 ov;
#pragma unroll
    for (int r = 0; r < 4; ++r) ov[r] = f2bf(o[jt][r]);
    *(u16x4*)(Opart + ob + jt * 16) = ov;
  }
  if (quad == 0) {
    ml[(size_t)u * 128 + w * 16 + b]      = m_run;
    ml[(size_t)u * 128 + 64 + w * 16 + b] = l_run;
  }
}

// ---------------- combine kv-split partials -> Ctx (bf16 [S,D]) ----------------
__global__ __launch_bounds__(256) void attn_combine_kernel(const u16* __restrict__ Opart,
                                                           const float* __restrict__ ml,
                                                           u16* __restrict__ Ctx) {
  const int hq = blockIdx.x;          // 0..1023
  const int h = hq >> 6, qt = hq & 63;
  int base;
  if (qt < 16)      base = qt;
  else if (qt < 32) base = 2 * qt - 16;
  else if (qt < 48) base = 3 * qt - 48;
  else              base = 4 * qt - 96;
  base += h * 160;
  const int nc = 1 + (qt >> 4);

  const int tid = threadIdx.x;
  const int row = tid >> 2;           // 0..63
  const int dg  = (tid & 3) * 16;     // d-group base

  float M = -3.0e38f;
  for (int ci = 0; ci < nc; ++ci)
    M = fmaxf(M, ml[(size_t)(base + ci) * 128 + row]);

  float L = 0.f;
  float acc[16];
#pragma unroll
  for (int i = 0; i < 16; ++i) acc[i] = 0.f;

  for (int ci = 0; ci < nc; ++ci) {
    float mp = ml[(size_t)(base + ci) * 128 + row];
    float lp = ml[(size_t)(base + ci) * 128 + 64 + row];
    float wgt = fexp2(mp - M);
    L += lp * wgt;
    const u16* op = Opart + (size_t)(base + ci) * 4096 + row * 64 + dg;
    u16x8 v0 = *(const u16x8*)op;
    u16x8 v1 = *(const u16x8*)(op + 8);
#pragma unroll
    for (int i = 0; i < 8; ++i) acc[i] += bf2f(v0[i]) * wgt;
#pragma unroll
    for (int i = 0; i < 8; ++i) acc[i + 8] += bf2f(v1[i]) * wgt;
  }
  const float inv = 1.f / L;
  u16x8 o0, o1;
#pragma unroll
  for (int i = 0; i < 8; ++i) { o0[i] = f2bf(acc[i] * inv); o1[i] = f2bf(acc[i + 8] * inv); }
  u16* dst = Ctx + (size_t)(qt * 64 + row) * D_DIM + h * HD + dg;
  *(u16x8*)dst = o0;
  *(u16x8*)(dst + 8) = o1;
}

// ---------------- output projection: out = ctx Wo^T + bo (fp32 out) ----------
__global__ __launch_bounds__(256) void gemm_out_kernel(const u16* __restrict__ Ctx,
                                                       const u16* __restrict__ Wo,
                                                       const float* __restrict__ bo,
                                                       float* __restrict__ out) {
  __shared__ __align__(16) u16 As[128 * 32];
  __shared__ __align__(16) u16 Bs[128 * 32];
  const int n0 = blockIdx.x * 128, m0 = blockIdx.y * 128;

  const f32x4 zero4 = {0.f, 0.f, 0.f, 0.f};
  f32x4 acc[4][4];
#pragma unroll
  for (int i = 0; i < 4; ++i)
#pragma unroll
    for (int j = 0; j < 4; ++j) acc[i][j] = zero4;

  gemm_core(Ctx, Wo, m0, n0, D_DIM, As, Bs, acc);

  const int lane = threadIdx.x & 63;
  const int wv = threadIdx.x >> 6, wr = wv >> 1, wc = wv & 1;
  const int b = lane & 15, quad = lane >> 4;

#pragma unroll
  for (int j = 0; j < 4; ++j) {
    int col = n0 + wc * 64 + j * 16 + b;
    float bias = bo[col];
#pragma unroll
    for (int i = 0; i < 4; ++i)
#pragma unroll
      for (int r = 0; r < 4; ++r) {
        int row = m0 + wr * 64 + i * 16 + quad * 4 + r;
        out[(size_t)row * D_DIM + col] = acc[i][j][r] + bias;
      }
  }
}

// ---------------- launcher ----------------
extern "C" void kernel_launch(void* const* d_in, const int* in_sizes, int n_in,
                              void* d_out, int out_size, void* d_ws, size_t ws_size,
                              hipStream_t stream) {
  const float* x  = (const float*)d_in[0];
  const float* Wq = (const float*)d_in[1];
  const float* Wk = (const float*)d_in[2];
  const float* Wv = (const float*)d_in[3];
  const float* Wo = (const float*)d_in[4];
  const float* bo = (const float*)d_in[5];
  float* out = (float*)d_out;

  char* ws = (char*)d_ws;
  const size_t MB = 1u << 20;
  u16*   Xb    = (u16*)(ws + 0 * MB);
  u16*   Wqb   = (u16*)(ws + 8 * MB);
  u16*   Wkb   = (u16*)(ws + 10 * MB);
  u16*   Wvb   = (u16*)(ws + 12 * MB);
  u16*   Wob   = (u16*)(ws + 14 * MB);
  u16*   Qb    = (u16*)(ws + 16 * MB);   // [S,D], scaled by log2e/8
  u16*   Kb    = (u16*)(ws + 24 * MB);   // [S,D]
  u16*   Vtb   = (u16*)(ws + 32 * MB);   // [D,S]
  u16*   Cxb   = (u16*)(ws + 40 * MB);   // [S,D]
  u16*   Opart = (u16*)(ws + 48 * MB);   // 2560 x [64 q][64 d]
  float* mlbuf = (float*)(ws + 68 * MB); // 2560 x (m[64], l[64])

  conv_kernel<<<4096, 256, 0, stream>>>(x,  Xb,  (S_LEN * D_DIM) / 4);
  conv_kernel<<<1024, 256, 0, stream>>>(Wq, Wqb, (D_DIM * D_DIM) / 4);
  conv_kernel<<<1024, 256, 0, stream>>>(Wk, Wkb, (D_DIM * D_DIM) / 4);
  conv_kernel<<<1024, 256, 0, stream>>>(Wv, Wvb, (D_DIM * D_DIM) / 4);
  conv_kernel<<<1024, 256, 0, stream>>>(Wo, Wob, (D_DIM * D_DIM) / 4);

  gemm_qkv_kernel<<<dim3(D_DIM / 128, S_LEN / 128, 3), 256, 0, stream>>>(
      Xb, Wqb, Wkb, Wvb, Qb, Kb, Vtb);

  attn_kernel<<<dim3(2560), 256, 0, stream>>>(Qb, Kb, Vtb, Opart, mlbuf);

  attn_combine_kernel<<<dim3(1024), 256, 0, stream>>>(Opart, mlbuf, Cxb);

  gemm_out_kernel<<<dim3(D_DIM / 128, S_LEN / 128), 256, 0, stream>>>(Cxb, Wob, bo, out);
}

// Round 4
// 214.067 us; speedup vs baseline: 1.8176x; 1.1621x over previous
//
#include <hip/hip_runtime.h>
#include <stdint.h>

typedef unsigned short u16;
typedef __attribute__((ext_vector_type(4))) unsigned short u16x4;
typedef __attribute__((ext_vector_type(8))) unsigned short u16x8;
typedef __attribute__((ext_vector_type(8))) __bf16 bf16x8;
typedef __attribute__((ext_vector_type(4))) float f32x4;

#define S_LEN 4096
#define D_DIM 1024
#define NH    16
#define HD    64

__device__ __forceinline__ u16 f2bf(float f) {
  return __builtin_bit_cast(u16, (__bf16)f);   // hw RNE cvt on gfx950
}
__device__ __forceinline__ float bf2f(u16 v) {
  return __builtin_bit_cast(float, (uint32_t)v << 16);
}
__device__ __forceinline__ bf16x8 bc(u16x8 v) { return __builtin_bit_cast(bf16x8, v); }
__device__ __forceinline__ float fexp2(float x) { return __builtin_amdgcn_exp2f(x); }

// async global->LDS, 16B per lane; lds dest = wave-uniform base + lane*16B
__device__ __forceinline__ void gload16(const u16* g, u16* l) {
  __builtin_amdgcn_global_load_lds((__attribute__((address_space(1))) void*)g,
                                   (__attribute__((address_space(3))) void*)l, 16, 0, 0);
}

// ---------------- fp32 -> bf16 conversion (all 5 tensors, one dispatch) -------
__global__ __launch_bounds__(256) void conv_all_kernel(const float* __restrict__ x,
                                                       const float* __restrict__ Wq,
                                                       const float* __restrict__ Wk,
                                                       const float* __restrict__ Wv,
                                                       const float* __restrict__ Wo,
                                                       u16* __restrict__ Xb, u16* __restrict__ Wqb,
                                                       u16* __restrict__ Wkb, u16* __restrict__ Wvb,
                                                       u16* __restrict__ Wob) {
  int blk = blockIdx.x;
  const float* src;
  u16* dst;
  int i;
  if (blk < 4096) { src = x; dst = Xb; i = blk * 256 + threadIdx.x; }
  else {
    int wi = (blk - 4096) >> 10;
    int lb = (blk - 4096) & 1023;
    src = (wi == 0) ? Wq : (wi == 1) ? Wk : (wi == 2) ? Wv : Wo;
    dst = (wi == 0) ? Wqb : (wi == 1) ? Wkb : (wi == 2) ? Wvb : Wob;
    i = lb * 256 + threadIdx.x;
  }
  f32x4 v = ((const f32x4*)src)[i];
  u16x4 o;
  o[0] = f2bf(v[0]); o[1] = f2bf(v[1]); o[2] = f2bf(v[2]); o[3] = f2bf(v[3]);
  ((u16x4*)dst)[i] = o;
}

// ---------------- GEMM core: C[128x128] = A[M,K] * W[N,K]^T (bf16, fp32 acc) ----
// m97 pattern + bank-conflict-free placement: granule (row,c) lives at LDS col
// (c + (row>>1))&3; fetch side applies inverse, read side adds loop-invariant goff.
__device__ __forceinline__ void gemm_core(const u16* __restrict__ A,
                                          const u16* __restrict__ W,
                                          int m0, int n0, int Kd,
                                          u16* As, u16* Bs, f32x4 acc[4][4]) {
  const int tid  = threadIdx.x;
  const int lane = tid & 63;
  const int wv   = tid >> 6;
  const int wr   = wv >> 1, wc = wv & 1;
  const int b    = lane & 15, quad = lane >> 4;
  const int lrow = lane >> 2;
  const int cg   = ((lane & 3) - (lrow >> 1)) & 3;   // fetch-side swizzle
  const int goff = ((quad + (b >> 1)) & 3) * 8;      // read-side swizzle

  const u16* ga0 = A + (size_t)(m0 + wv * 16 + lrow) * Kd + cg * 8;
  const u16* ga1 = A + (size_t)(m0 + 64 + wv * 16 + lrow) * Kd + cg * 8;
  const u16* gb0 = W + (size_t)(n0 + wv * 16 + lrow) * Kd + cg * 8;
  const u16* gb1 = W + (size_t)(n0 + 64 + wv * 16 + lrow) * Kd + cg * 8;
  u16* la0 = As + wv * 512;
  u16* la1 = As + 2048 + wv * 512;
  u16* lb0 = Bs + wv * 512;
  u16* lb1 = Bs + 2048 + wv * 512;

  for (int k0 = 0; k0 < Kd; k0 += 32) {
    gload16(ga0 + k0, la0);
    gload16(ga1 + k0, la1);
    gload16(gb0 + k0, lb0);
    gload16(gb1 + k0, lb1);
    __syncthreads();   // drains vmcnt (DMA) for own wave + block barrier

    u16x8 af[4], bw[4];
#pragma unroll
    for (int i = 0; i < 4; ++i) {
      af[i] = *(const u16x8*)(As + (wr * 64 + i * 16 + b) * 32 + goff);
      bw[i] = *(const u16x8*)(Bs + (wc * 64 + i * 16 + b) * 32 + goff);
    }
#pragma unroll
    for (int i = 0; i < 4; ++i)
#pragma unroll
      for (int j = 0; j < 4; ++j)
        acc[i][j] = __builtin_amdgcn_mfma_f32_16x16x32_bf16(bc(af[i]), bc(bw[j]), acc[i][j], 0, 0, 0);
    __syncthreads();
  }
}

// ---------------- fused QKV projection ----------------
__global__ __launch_bounds__(256) void gemm_qkv_kernel(const u16* __restrict__ X,
                                                       const u16* __restrict__ Wq,
                                                       const u16* __restrict__ Wk,
                                                       const u16* __restrict__ Wv,
                                                       u16* __restrict__ Q,
                                                       u16* __restrict__ K,
                                                       u16* __restrict__ Vt) {
  __shared__ __align__(16) u16 As[128 * 32];
  __shared__ __align__(16) u16 Bs[128 * 32];
  const int z = blockIdx.z;
  const u16* W = (z == 0) ? Wq : (z == 1) ? Wk : Wv;
  const int n0 = blockIdx.x * 128, m0 = blockIdx.y * 128;

  const f32x4 zero4 = {0.f, 0.f, 0.f, 0.f};
  f32x4 acc[4][4];
#pragma unroll
  for (int i = 0; i < 4; ++i)
#pragma unroll
    for (int j = 0; j < 4; ++j) acc[i][j] = zero4;

  gemm_core(X, W, m0, n0, D_DIM, As, Bs, acc);

  const int lane = threadIdx.x & 63;
  const int wv = threadIdx.x >> 6, wr = wv >> 1, wc = wv & 1;
  const int b = lane & 15, quad = lane >> 4;

  if (z < 2) {
    u16* out = (z == 0) ? Q : K;
    const float sc = (z == 0) ? 0.18033688011112042f : 1.0f;  // 0.125*log2(e)
#pragma unroll
    for (int i = 0; i < 4; ++i)
#pragma unroll
      for (int j = 0; j < 4; ++j)
#pragma unroll
        for (int r = 0; r < 4; ++r) {
          int row = m0 + wr * 64 + i * 16 + quad * 4 + r;
          int col = n0 + wc * 64 + j * 16 + b;
          out[(size_t)row * D_DIM + col] = f2bf(acc[i][j][r] * sc);
        }
  } else {
#pragma unroll
    for (int i = 0; i < 4; ++i)
#pragma unroll
      for (int j = 0; j < 4; ++j) {
        int col = n0 + wc * 64 + j * 16 + b;           // d index
        int row = m0 + wr * 64 + i * 16 + quad * 4;    // s index (4 consecutive)
        u16x4 vv;
#pragma unroll
        for (int r = 0; r < 4; ++r) vv[r] = f2bf(acc[i][j][r]);
        *(u16x4*)(Vt + (size_t)col * S_LEN + row) = vv;
      }
  }
}

// ---------------- flash attention, kv-split, q-tile 128, 8 waves (causal) ------
// S^T = K Q^T, O^T = V^T P^T (per-lane scalar softmax stats). 8 waves share one
// 64-kv K/V stage per barrier (2 DMAs/wave). Swizzled conflict-free placement.
// Units: (head, 128-q-tile, <=16-kv-tile chunk) -> 1280 balanced blocks.
__global__ __launch_bounds__(512) void attn_kernel(const u16* __restrict__ Q,
                                                   const u16* __restrict__ K,
                                                   const u16* __restrict__ Vt,
                                                   u16* __restrict__ Opart,
                                                   float* __restrict__ ml) {
  const int u = (int)gridDim.x - 1 - (int)blockIdx.x;  // long chunks first
  const int h = u / 80;
  const int uu = u - h * 80;
  int qt, c;
  if (uu < 8)       { qt = uu;                    c = 0; }
  else if (uu < 24) { qt = 8 + ((uu - 8) >> 1);   c = (uu - 8) & 1; }
  else if (uu < 48) { qt = 16 + (uu - 24) / 3;    c = (uu - 24) % 3; }
  else              { qt = 24 + ((uu - 48) >> 2); c = (uu - 48) & 3; }
  const int t0 = c * 16;
  const int t_end = min(t0 + 16, 2 * qt + 2);
  const int q0 = qt * 128;

  const int tid = threadIdx.x, lane = tid & 63, w = tid >> 6;   // w = 0..7
  const int quad = lane >> 4, b = lane & 15;
  const int lrow = lane >> 2;
  const int cg   = ((lane & 3) - (lrow >> 1)) & 3;   // fetch-side swizzle
  const int goff = ((quad + (b >> 1)) & 3) * 8;      // read-side swizzle

  __shared__ __align__(16) u16 Ks[2 * 4096];   // [buf][ks_d][kv 64][32] swizzled
  __shared__ __align__(16) u16 Vts[2 * 4096];  // [buf][ks_kv][d 64][32] swizzled
  __shared__ __align__(16) u16 Ps[8][16 * 72]; // per-wave [q 16][kv 64+pad]

  // staging assignment: wave w handles K chunk (ks=w&1, rows (w>>1)*16..) + same V chunk
  const int ksg = w & 1, rg = w >> 1;
  const u16* kgb = K + (size_t)(rg * 16 + lrow) * D_DIM + h * HD + ksg * 32 + cg * 8;
  const u16* vgb = Vt + (size_t)(h * HD + rg * 16 + lrow) * S_LEN + ksg * 32 + cg * 8;
  u16* const ldk = Ks + ksg * 2048 + rg * 512;
  u16* const ldv = Vts + ksg * 2048 + rg * 512;

  // Q fragments (B-operand): n = q row = q0 + w*16 + b, k = d = ks*32 + quad*8 + j
  u16x8 bq[2];
  {
    const size_t qbase = (size_t)(q0 + w * 16 + b) * D_DIM + h * HD + quad * 8;
    bq[0] = *(const u16x8*)(Q + qbase);
    bq[1] = *(const u16x8*)(Q + qbase + 32);
  }

  const f32x4 zero4 = {0.f, 0.f, 0.f, 0.f};
  f32x4 o[4];   // O^T tiles: row = d = jt*16+quad*4+r, col = q = b
#pragma unroll
  for (int jt = 0; jt < 4; ++jt) o[jt] = zero4;
  float m_run = -3.0e38f, l_run = 0.f;

  auto stage = [&](int t, int bsel) {
    gload16(kgb + (size_t)t * 64 * D_DIM, ldk + bsel * 4096);
    gload16(vgb + t * 64, ldv + bsel * 4096);
  };

  u16* PsW = &Ps[w][0];
  const int qg = q0 + w * 16 + b;        // this lane's q row
  const int qg_wmax = q0 + w * 16 + 15;  // wave's max q row
  stage(t0, 0);
  int buf = 0;

  for (int t = t0; t < t_end; ++t) {
    __syncthreads();   // own-wave vmcnt drain + block barrier: buf is ready
    if (t + 1 < t_end) stage(t + 1, buf ^ 1);

    if (t * 64 <= qg_wmax) {   // wave not fully masked (wave-uniform)
      const u16* KB = Ks + buf * 4096;
      const u16* VB = Vts + buf * 4096;

      // ---- S^T = K Q^T : s[jt] rows = kv jt*16..+15, cols = 16 q rows ----
      f32x4 s[4];
#pragma unroll
      for (int jt = 0; jt < 4; ++jt) {
        s[jt] = zero4;
#pragma unroll
        for (int ks = 0; ks < 2; ++ks) {
          u16x8 ak = *(const u16x8*)(KB + ks * 2048 + jt * 512 + b * 32 + goff);
          s[jt] = __builtin_amdgcn_mfma_f32_16x16x32_bf16(bc(ak), bc(bq[ks]), s[jt], 0, 0, 0);
        }
      }

      // ---- causal mask (only when tile straddles this lane's diagonal) ----
      if (t * 64 + 63 > qg) {
        const int kvb = t * 64 + quad * 4;
#pragma unroll
        for (int jt = 0; jt < 4; ++jt)
#pragma unroll
          for (int r = 0; r < 4; ++r)
            if (kvb + jt * 16 + r > qg) s[jt][r] = -1.0e30f;
      }

      // ---- online softmax (exp2 domain), per-lane scalar stats ----
      float mx = s[0][0];
#pragma unroll
      for (int jt = 0; jt < 4; ++jt)
#pragma unroll
        for (int r = 0; r < 4; ++r) mx = fmaxf(mx, s[jt][r]);
      mx = fmaxf(mx, __shfl_xor(mx, 16));
      mx = fmaxf(mx, __shfl_xor(mx, 32));

      const float mn = fmaxf(m_run, mx);
      const float alpha = fexp2(m_run - mn);
      m_run = mn;

      float sum = 0.f;
#pragma unroll
      for (int jt = 0; jt < 4; ++jt) {
        u16x4 pk;
#pragma unroll
        for (int r = 0; r < 4; ++r) {
          float p = fexp2(s[jt][r] - mn);
          sum += p;
          pk[r] = f2bf(p);
        }
        *(u16x4*)(PsW + b * 72 + jt * 16 + quad * 4) = pk;   // Ps[q=b][kv]
      }
      sum += __shfl_xor(sum, 16);
      sum += __shfl_xor(sum, 32);
      l_run = l_run * alpha + sum;

#pragma unroll
      for (int jt = 0; jt < 4; ++jt) o[jt] *= alpha;

      // ---- O^T += V^T P^T ----
      u16x8 bp[2];
      bp[0] = *(const u16x8*)(PsW + b * 72 + quad * 8);        // B: k=kv, n=q=b
      bp[1] = *(const u16x8*)(PsW + b * 72 + 32 + quad * 8);
#pragma unroll
      for (int jt = 0; jt < 4; ++jt)
#pragma unroll
        for (int ks = 0; ks < 2; ++ks) {
          u16x8 av = *(const u16x8*)(VB + ks * 2048 + jt * 512 + b * 32 + goff);
          o[jt] = __builtin_amdgcn_mfma_f32_16x16x32_bf16(bc(av), bc(bp[ks]), o[jt], 0, 0, 0);
        }
    }
    buf ^= 1;
  }

  // ---- write partials: Opart unit layout [q 128][d 64] ----
  const size_t ob = (size_t)u * 8192 + (size_t)(w * 16 + b) * 64 + quad * 4;
#pragma unroll
  for (int jt = 0; jt < 4; ++jt) {
    u16x4 ov;
#pragma unroll
    for (int r = 0; r < 4; ++r) ov[r] = f2bf(o[jt][r]);
    *(u16x4*)(Opart + ob + jt * 16) = ov;
  }
  if (quad == 0) {
    ml[(size_t)u * 256 + w * 16 + b]       = m_run;
    ml[(size_t)u * 256 + 128 + w * 16 + b] = l_run;
  }
}

// ---------------- combine kv-split partials -> Ctx (bf16 [S,D]) ----------------
__global__ __launch_bounds__(256) void attn_combine_kernel(const u16* __restrict__ Opart,
                                                           const float* __restrict__ ml,
                                                           u16* __restrict__ Ctx) {
  const int hq = blockIdx.x;          // 0..1023: (h, 64-row q-tile)
  const int h = hq >> 6, qt64 = hq & 63;
  const int qt = qt64 >> 1;           // 128-row q-tile index
  int base;
  if (qt < 8)       base = qt;
  else if (qt < 16) base = 2 * qt - 8;
  else if (qt < 24) base = 3 * qt - 24;
  else              base = 4 * qt - 48;
  base += h * 80;
  const int nc = 1 + (qt >> 3);

  const int tid = threadIdx.x;
  const int row = tid >> 2;                    // 0..63
  const int urow = (qt64 & 1) * 64 + row;      // row within 128-q unit
  const int dg  = (tid & 3) * 16;              // d-group base

  float M = -3.0e38f;
  for (int ci = 0; ci < nc; ++ci)
    M = fmaxf(M, ml[(size_t)(base + ci) * 256 + urow]);

  float L = 0.f;
  float acc[16];
#pragma unroll
  for (int i = 0; i < 16; ++i) acc[i] = 0.f;

  for (int ci = 0; ci < nc; ++ci) {
    float mp = ml[(size_t)(base + ci) * 256 + urow];
    float lp = ml[(size_t)(base + ci) * 256 + 128 + urow];
    float wgt = fexp2(mp - M);
    L += lp * wgt;
    const u16* op = Opart + (size_t)(base + ci) * 8192 + (size_t)urow * 64 + dg;
    u16x8 v0 = *(const u16x8*)op;
    u16x8 v1 = *(const u16x8*)(op + 8);
#pragma unroll
    for (int i = 0; i < 8; ++i) acc[i] += bf2f(v0[i]) * wgt;
#pragma unroll
    for (int i = 0; i < 8; ++i) acc[i + 8] += bf2f(v1[i]) * wgt;
  }
  const float inv = 1.f / L;
  u16x8 o0, o1;
#pragma unroll
  for (int i = 0; i < 8; ++i) { o0[i] = f2bf(acc[i] * inv); o1[i] = f2bf(acc[i + 8] * inv); }
  u16* dst = Ctx + (size_t)(qt64 * 64 + row) * D_DIM + h * HD + dg;
  *(u16x8*)dst = o0;
  *(u16x8*)(dst + 8) = o1;
}

// ---------------- output projection: out = ctx Wo^T + bo (fp32 out) ----------
__global__ __launch_bounds__(256) void gemm_out_kernel(const u16* __restrict__ Ctx,
                                                       const u16* __restrict__ Wo,
                                                       const float* __restrict__ bo,
                                                       float* __restrict__ out) {
  __shared__ __align__(16) u16 As[128 * 32];
  __shared__ __align__(16) u16 Bs[128 * 32];
  const int n0 = blockIdx.x * 128, m0 = blockIdx.y * 128;

  const f32x4 zero4 = {0.f, 0.f, 0.f, 0.f};
  f32x4 acc[4][4];
#pragma unroll
  for (int i = 0; i < 4; ++i)
#pragma unroll
    for (int j = 0; j < 4; ++j) acc[i][j] = zero4;

  gemm_core(Ctx, Wo, m0, n0, D_DIM, As, Bs, acc);

  const int lane = threadIdx.x & 63;
  const int wv = threadIdx.x >> 6, wr = wv >> 1, wc = wv & 1;
  const int b = lane & 15, quad = lane >> 4;

#pragma unroll
  for (int j = 0; j < 4; ++j) {
    int col = n0 + wc * 64 + j * 16 + b;
    float bias = bo[col];
#pragma unroll
    for (int i = 0; i < 4; ++i)
#pragma unroll
      for (int r = 0; r < 4; ++r) {
        int row = m0 + wr * 64 + i * 16 + quad * 4 + r;
        out[(size_t)row * D_DIM + col] = acc[i][j][r] + bias;
      }
  }
}

// ---------------- launcher ----------------
extern "C" void kernel_launch(void* const* d_in, const int* in_sizes, int n_in,
                              void* d_out, int out_size, void* d_ws, size_t ws_size,
                              hipStream_t stream) {
  const float* x  = (const float*)d_in[0];
  const float* Wq = (const float*)d_in[1];
  const float* Wk = (const float*)d_in[2];
  const float* Wv = (const float*)d_in[3];
  const float* Wo = (const float*)d_in[4];
  const float* bo = (const float*)d_in[5];
  float* out = (float*)d_out;

  char* ws = (char*)d_ws;
  const size_t MB = 1u << 20;
  u16*   Xb    = (u16*)(ws + 0 * MB);
  u16*   Wqb   = (u16*)(ws + 8 * MB);
  u16*   Wkb   = (u16*)(ws + 10 * MB);
  u16*   Wvb   = (u16*)(ws + 12 * MB);
  u16*   Wob   = (u16*)(ws + 14 * MB);
  u16*   Qb    = (u16*)(ws + 16 * MB);   // [S,D], scaled by log2e/8
  u16*   Kb    = (u16*)(ws + 24 * MB);   // [S,D]
  u16*   Vtb   = (u16*)(ws + 32 * MB);   // [D,S]
  u16*   Cxb   = (u16*)(ws + 40 * MB);   // [S,D]
  u16*   Opart = (u16*)(ws + 48 * MB);   // 1280 units x [128 q][64 d] = 20 MB
  float* mlbuf = (float*)(ws + 68 * MB); // 1280 x (m[128], l[128]) = 1.25 MB

  conv_all_kernel<<<8192, 256, 0, stream>>>(x, Wq, Wk, Wv, Wo, Xb, Wqb, Wkb, Wvb, Wob);

  gemm_qkv_kernel<<<dim3(D_DIM / 128, S_LEN / 128, 3), 256, 0, stream>>>(
      Xb, Wqb, Wkb, Wvb, Qb, Kb, Vtb);

  attn_kernel<<<dim3(1280), 512, 0, stream>>>(Qb, Kb, Vtb, Opart, mlbuf);

  attn_combine_kernel<<<dim3(1024), 256, 0, stream>>>(Opart, mlbuf, Cxb);

  gemm_out_kernel<<<dim3(D_DIM / 128, S_LEN / 128), 256, 0, stream>>>(Cxb, Wob, bo, out);
}